// Round 9
// baseline (124.994 us; speedup 1.0000x reference)
//
#include <hip/hip_runtime.h>

#define N_NODES 10000
#define N_EDGES 640000
#define D 128
#define BN_EPS 1e-5f
#define CAP 128        // slots per node; deg ~ Poisson(64), max ~110
#define NSTRIPE 16     // striped BN-stat copies
#define RPB 4          // R19: nodes per block in k_gfill (was 8)
#define NB 2500        // k_gfill blocks: 4 nodes each (2500*4 = 10000 exact)
#define NBC 157        // coarse bins of 64 nodes (d>>6; 157*64 = 10048)
#define BCAPC 4608     // record capacity per coarse bin (mean 4076, +8.3 sigma)
#define ABLK 256       // pass-A blocks
#define ASLICE 2500    // edges per pass-A block (256*2500 = 640000)
#define CSENT 1250     // untouched cur[] slot = uniform ws fill value (poison base)

typedef _Float16 half8_t __attribute__((ext_vector_type(8)));
typedef float f32x4 __attribute__((ext_vector_type(4)));   // NT-capable float4
typedef unsigned short u16;

// =====================================================================
// K1: bin edges by dst>>6 (COARSE 64-node bins) + x->fp16.  R14-exact.
// Record = (s<<6)|(d&63): bits 0-1 = node-in-4, bits 2-5 = sub-bin-4.
// =====================================================================
__global__ __launch_bounds__(256) void k_bin(
    const int* __restrict__ ei,
    const float4* __restrict__ x4,
    int* cur,                      // [1280], poison-based cursors (0..156 used)
    int* __restrict__ recs,        // [NBC*BCAPC], packed (s<<6 | d&63)
    half8_t* __restrict__ xh)
{
    __shared__ int cnt[NBC];       // per-bin count, then local cursor
    __shared__ int base_[NBC];     // global reserved start (rel. to poison base)
    __shared__ int loff[NBC];      // exclusive prefix sum (LDS sort offsets)
    __shared__ int sc[256];        // scan scratch
    __shared__ int sorted[ASLICE]; // 10 KB: block's records sorted by bin
    const int b = blockIdx.x, t = threadIdx.x;

    // x -> fp16 (coalesced 16B stores; ~2.5 half8 per thread)
    {
        const int n8 = N_NODES * D / 8;    // 160000
        for (int i = b * 256 + t; i < n8; i += ABLK * 256) {
            const float4 a = x4[2 * i];
            const float4 c = x4[2 * i + 1];
            half8_t h;
            h[0] = (_Float16)a.x; h[1] = (_Float16)a.y;
            h[2] = (_Float16)a.z; h[3] = (_Float16)a.w;
            h[4] = (_Float16)c.x; h[5] = (_Float16)c.y;
            h[6] = (_Float16)c.z; h[7] = (_Float16)c.w;
            xh[i] = h;
        }
    }

    if (t < NBC) cnt[t] = 0;
    __syncthreads();

    // ---- count pass ----
    const int e0 = b * ASLICE;
    for (int i = t; i < ASLICE; i += 256)
        atomicAdd(&cnt[ei[N_EDGES + e0 + i] >> 6], 1);
    __syncthreads();

    // ---- exclusive prefix sum (Hillis-Steele over padded 256) ----
    sc[t] = (t < NBC) ? cnt[t] : 0;
    __syncthreads();
    #pragma unroll
    for (int off = 1; off < 256; off <<= 1) {
        const int add = (t >= off) ? sc[t - off] : 0;
        __syncthreads();
        sc[t] += add;
        __syncthreads();
    }

    // ---- global reserve + init local cursors ----
    const unsigned cbase = (unsigned)cur[CSENT];
    if (t < NBC) {
        loff[t]  = sc[t] - cnt[t];                 // exclusive
        base_[t] = (int)((unsigned)atomicAdd(&cur[t], cnt[t]) - cbase);
        cnt[t]   = 0;                              // reuse as local cursor
    }
    __syncthreads();

    // ---- scatter into LDS (sorted by bin) ----
    for (int i = t; i < ASLICE; i += 256) {
        const int e = e0 + i;
        const int d = ei[N_EDGES + e];
        const int s = ei[e];
        const int bin = d >> 6;
        const int p = atomicAdd(&cnt[bin], 1);
        sorted[loff[bin] + p] = (s << 6) | (d & 63);
    }
    __syncthreads();

    // ---- flush: 16-lane groups write contiguous per-bin runs ----
    const int g = t >> 4, sl = t & 15;
    for (int bin = g; bin < NBC; bin += 16) {
        const int c  = cnt[bin];
        const int gb = base_[bin];
        const int lo = loff[bin];
        for (int k = sl; k < c; k += 16) {
            const int pos = gb + k;
            if (pos < BCAPC) recs[bin * BCAPC + pos] = sorted[lo + k];
        }
    }
}

// =====================================================================
// K2: fill + gather + MLP + striped BN-stat partials.
// R19: RPB 8 -> 4 (2500 blocks). The round-0..18 arc proved per-wave
// ILP was never the limiter: 1250 blocks x 4 waves = 5000 waves vs
// 8192 slots (<=61% at t=0; measured 30-44%), per-bin LATENCY is the
// cost, and TLP was the missing hider. One wave per node (no j-loop),
// gather/MLP inner code R14-exact. LDS ~3.4KB -> 8 blocks/CU (wave-
// slot-capped), grid supplies 9.8 -> near-full occupancy, ~2x waves.
// Cost: coarse-bin scan redundancy x2 (+20MB L2, ~+3us chip-wide).
// =====================================================================
__global__ __launch_bounds__(256) void k_gfill(
    const float* __restrict__ x,
    const half8_t* __restrict__ xh8,
    const int* __restrict__ cur,
    const int* __restrict__ recs,
    const float* __restrict__ W,
    const float* __restrict__ bias,
    float* __restrict__ out,     // pre-BN h, fp32
    float* __restrict__ stats)   // [NSTRIPE][256] + sentinel
{
    __shared__ u16 lst[RPB * CAP];   // 1 KB: per-node src lists
    __shared__ int cnt[RPB];
    __shared__ float hs[RPB][D];     // 2 KB: gathered rows
    __shared__ float red[512];       // reduce scratch
    const int tid  = threadIdx.x;
    const int bin  = blockIdx.x;
    const int cb   = bin >> 4;           // coarse bin (64 nodes)
    const int sub  = bin & 15;           // this block's 4-node slice
    const int wv   = tid >> 6;           // wave = node 0..3
    const int lane = tid & 63;
    const int qq   = lane >> 4;          // quad 0..3: which edge of a 4-edge group
    const int l    = lane & 15;          // owns cols 8l..8l+7
    const float4* __restrict__ x4 = (const float4*)x;

    if (tid < RPB) cnt[tid] = 0;
    __syncthreads();

    // ---- Fill: scan coarse bin's records, keep this sub-bin's ----
    const unsigned cbase = (unsigned)cur[CSENT];
    int nrec = (int)((unsigned)cur[cb] - cbase);
    if (nrec > BCAPC) nrec = BCAPC;
    const int* __restrict__ br = recs + cb * BCAPC;
    for (int i = tid; i < nrec; i += 256) {
        const int r = br[i];
        if (((r >> 2) & 15) == sub) {
            const int p = atomicAdd(&cnt[r & 3], 1);
            if (p < CAP) lst[(r & 3) * CAP + p] = (u16)(r >> 6);
        }
    }
    __syncthreads();

    // ---- Gather: wave wv handles node wv (R14-exact inner loop) ----
    {
        const int lrow = wv;
        const int node = bin * RPB + lrow;
        int n = cnt[lrow];
        if (n > CAP) n = CAP;
        const u16* __restrict__ myl = &lst[lrow * CAP];
        float acc[8];
        #pragma unroll
        for (int z = 0; z < 8; z++) acc[z] = 0.f;

        int i = 0;
        for (; i + 64 <= n; i += 64) {       // full 64-edge chunk: 16 quads
            const int sj = (int)myl[i + lane];
            #pragma unroll
            for (int b = 0; b < 2; b++) {
                half8_t v[8];
                #pragma unroll
                for (int u = 0; u < 8; u++) {
                    const int s = __shfl(sj, 4 * (b * 8 + u) + qq, 64);
                    v[u] = xh8[(size_t)s * 16 + l];   // 16B, 8 in flight x 4 rows
                }
                #pragma unroll
                for (int u = 0; u < 8; u++)
                    #pragma unroll
                    for (int z = 0; z < 8; z++)
                        acc[z] += (float)v[u][z];
            }
        }
        const int c = n - i;
        if (c > 0) {
            const int sj = (lane < c) ? (int)myl[i + lane] : 0;
            const int quads = c >> 2;
            for (int t2 = 0; t2 < quads; t2 += 8) {
                half8_t v[8];
                #pragma unroll
                for (int u = 0; u < 8; u++) {
                    const int s = __shfl(sj, (4 * (t2 + u) + qq) & 63, 64);
                    v[u] = xh8[(size_t)s * 16 + l];   // safe addr (sj=0 pad)
                }
                #pragma unroll
                for (int u = 0; u < 8; u++) {
                    if (t2 + u < quads) {             // wave-uniform predicate
                        #pragma unroll
                        for (int z = 0; z < 8; z++)
                            acc[z] += (float)v[u][z];
                    }
                }
            }
            const int r = c & 3;
            if (r > 0) {                              // last 1-3 edges
                const int s = __shfl(sj, (4 * quads + qq) & 63, 64);
                const half8_t vv = xh8[(size_t)s * 16 + l];
                if (qq < r) {
                    #pragma unroll
                    for (int z = 0; z < 8; z++)
                        acc[z] += (float)vv[z];
                }
            }
        }
        // combine the 4 quad groups
        #pragma unroll
        for (int z = 0; z < 8; z++) {
            acc[z] += __shfl_xor(acc[z], 16, 64);
            acc[z] += __shfl_xor(acc[z], 32, 64);
        }
        if (qq == 0) {
            const float4 xa = x4[(size_t)node * 32 + 2 * l];      // self term fp32
            const float4 xb = x4[(size_t)node * 32 + 2 * l + 1];  // (eps = 0)
            *(float4*)&hs[lrow][8 * l] =
                make_float4(acc[0] + xa.x, acc[1] + xa.y, acc[2] + xa.z, acc[3] + xa.w);
            *(float4*)&hs[lrow][8 * l + 4] =
                make_float4(acc[4] + xb.x, acc[5] + xb.y, acc[6] + xb.z, acc[7] + xb.w);
        }
    }
    __syncthreads();

    // ---- MLP: thread owns col = tid&127, rows rg*2, rg*2+1 ----
    const int col = tid & 127;
    const int rg  = tid >> 7;            // 0 or 1
    float a[2] = {0.f, 0.f};
    #pragma unroll 8
    for (int k = 0; k < D; k++) {
        const float w = W[k * D + col];        // 256B/wave coalesced, L1/L2-hot
        #pragma unroll
        for (int r = 0; r < 2; r++)
            a[r] = fmaf(hs[rg * 2 + r][k], w, a[r]);   // LDS broadcast
    }

    const float bcol = bias[col];
    float s1 = 0.f, s2 = 0.f;
    #pragma unroll
    for (int r = 0; r < 2; r++) {
        const float v = fmaxf(a[r] + bcol, 0.f);
        __builtin_nontemporal_store(v, &out[(size_t)(bin * RPB + rg * 2 + r) * D + col]);
        s1 += v;
        s2 += v * v;
    }

    // ---- BN stat partials: block-reduce, striped atomics ----
    __syncthreads();
    red[tid]       = s1;
    red[256 + tid] = s2;
    __syncthreads();
    if (tid < D) {
        float* sp = &stats[(size_t)(bin & (NSTRIPE - 1)) * 256];
        atomicAdd(&sp[tid],     red[tid]       + red[tid + 128]);
        atomicAdd(&sp[D + tid], red[256 + tid] + red[256 + tid + 128]);
    }
}

// =====================================================================
// K3: reduce NSTRIPE stat copies (minus poison base) + BN apply.
// Pure stream over out: nt both directions (native ext-vector type —
// HIP's float4 class is rejected by the nontemporal builtins).
// =====================================================================
__global__ __launch_bounds__(256) void k_bn(
    float* out,
    const float* __restrict__ stats,
    const float* __restrict__ gamma,
    const float* __restrict__ beta)
{
    __shared__ float sc_[D], sh[D];
    const int tid = threadIdx.x;
    if (tid < D) {
        const float fbase = stats[NSTRIPE * 256];   // untouched sentinel
        float s = 0.f, q = 0.f;
        #pragma unroll
        for (int cp = 0; cp < NSTRIPE; cp++) {
            s += stats[cp * 256 + tid]     - fbase;
            q += stats[cp * 256 + D + tid] - fbase;
        }
        const float mean = s * (1.0f / N_NODES);
        const float var  = q * (1.0f / N_NODES) - mean * mean;
        const float scale = gamma[tid] * rsqrtf(var + BN_EPS);
        sc_[tid] = scale;
        sh[tid] = beta[tid] - mean * scale;
    }
    __syncthreads();

    f32x4* o4 = (f32x4*)out;
    #pragma unroll
    for (int j = 0; j < 2; j++) {
        const int f = blockIdx.x * 512 + j * 256 + tid;
        const int c = (f & 31) << 2;
        f32x4 v = __builtin_nontemporal_load(&o4[f]);
        v.x = v.x * sc_[c]     + sh[c];
        v.y = v.y * sc_[c + 1] + sh[c + 1];
        v.z = v.z * sc_[c + 2] + sh[c + 2];
        v.w = v.w * sc_[c + 3] + sh[c + 3];
        __builtin_nontemporal_store(v, &o4[f]);
    }
}

extern "C" void kernel_launch(void* const* d_in, const int* in_sizes, int n_in,
                              void* d_out, int out_size, void* d_ws, size_t ws_size,
                              hipStream_t stream)
{
    const float* x     = (const float*)d_in[0];  // [10000,128] fp32
    const int*   ei    = (const int*)d_in[1];    // [2,640000] int32
    const float* W     = (const float*)d_in[2];  // [128,128] fp32
    const float* bias  = (const float*)d_in[3];  // [128] fp32
    const float* gamma = (const float*)d_in[4];  // [128] fp32
    const float* beta  = (const float*)d_in[5];  // [128] fp32
    float* out = (float*)d_out;                  // [10000,128] fp32

    // ws layout (~5.5 MB), no memset (poison sentinels):
    // [stats 16*256+8 f32][cur 1280 i32][recs NBC*BCAPC i32][xh 10000*128 fp16]
    float*   stats = (float*)d_ws;
    int*     cur   = (int*)(stats + NSTRIPE * 256 + 8);
    int*     recs  = cur + 1280;
    half8_t* xh    = (half8_t*)(recs + NBC * BCAPC);
    // xh byte offset = (4104 + 1280 + 723456)*4 = 2,915,360 -> 16B-aligned

    k_bin<<<ABLK, 256, 0, stream>>>(ei, (const float4*)x, cur, recs, xh);
    k_gfill<<<NB, 256, 0, stream>>>(x, xh, cur, recs, W, bias, out, stats);
    k_bn<<<N_NODES * D / 2048, 256, 0, stream>>>(out, stats, gamma, beta);
}

// Round 10
// 121.846 us; speedup vs baseline: 1.0258x; 1.0258x over previous
//
#include <hip/hip_runtime.h>

#define N_NODES 10000
#define N_EDGES 640000
#define D 128
#define BN_EPS 1e-5f
#define CAP 128        // slots per node; deg ~ Poisson(64), max ~110
#define NSTRIPE 16     // striped BN-stat copies
#define RPB 8          // nodes per block in k_gfill
#define NB 1250        // k_gfill blocks: 8 nodes each (1250*8 = 10000 exact)
#define NBC 157        // coarse bins of 64 nodes (d>>6; 157*64 = 10048)
#define BCAPC 4608     // record capacity per coarse bin (mean 4076, +8.3 sigma)
#define ABLK 256       // pass-A blocks
#define ASLICE 2500    // edges per pass-A block (256*2500 = 640000)
#define CSENT 1250     // untouched cur[] slot = uniform ws fill value (poison base)

typedef _Float16 half8_t __attribute__((ext_vector_type(8)));
typedef float f32x4 __attribute__((ext_vector_type(4)));   // NT-capable float4
typedef unsigned short u16;

static __device__ __forceinline__ float rdlane(float v, int k) {
    return __uint_as_float(__builtin_amdgcn_readlane(__float_as_uint(v), k));
}

// =====================================================================
// K1: bin edges by dst>>6 (COARSE 64-node bins) + x->fp16.  R14-exact
// (best measured config: 116.6us total). Discard pile from R13-R19:
// k_bin occupancy, store-coalescing, atomic-free layouts, gather ILP
// (x3), gather TLP — all neutral-to-worse vs this structure.
// Record = (s<<6)|(d&63): low 3 bits = node-in-8, bits 3..5 = sub-bin.
// =====================================================================
__global__ __launch_bounds__(256) void k_bin(
    const int* __restrict__ ei,
    const float4* __restrict__ x4,
    int* cur,                      // [1280], poison-based cursors (0..156 used)
    int* __restrict__ recs,        // [NBC*BCAPC], packed (s<<6 | d&63)
    half8_t* __restrict__ xh)
{
    __shared__ int cnt[NBC];       // per-bin count, then local cursor
    __shared__ int base_[NBC];     // global reserved start (rel. to poison base)
    __shared__ int loff[NBC];      // exclusive prefix sum (LDS sort offsets)
    __shared__ int sc[256];        // scan scratch
    __shared__ int sorted[ASLICE]; // 10 KB: block's records sorted by bin
    const int b = blockIdx.x, t = threadIdx.x;

    // x -> fp16 (coalesced 16B stores; ~2.5 half8 per thread)
    {
        const int n8 = N_NODES * D / 8;    // 160000
        for (int i = b * 256 + t; i < n8; i += ABLK * 256) {
            const float4 a = x4[2 * i];
            const float4 c = x4[2 * i + 1];
            half8_t h;
            h[0] = (_Float16)a.x; h[1] = (_Float16)a.y;
            h[2] = (_Float16)a.z; h[3] = (_Float16)a.w;
            h[4] = (_Float16)c.x; h[5] = (_Float16)c.y;
            h[6] = (_Float16)c.z; h[7] = (_Float16)c.w;
            xh[i] = h;
        }
    }

    if (t < NBC) cnt[t] = 0;
    __syncthreads();

    // ---- count pass ----
    const int e0 = b * ASLICE;
    for (int i = t; i < ASLICE; i += 256)
        atomicAdd(&cnt[ei[N_EDGES + e0 + i] >> 6], 1);
    __syncthreads();

    // ---- exclusive prefix sum (Hillis-Steele over padded 256) ----
    sc[t] = (t < NBC) ? cnt[t] : 0;
    __syncthreads();
    #pragma unroll
    for (int off = 1; off < 256; off <<= 1) {
        const int add = (t >= off) ? sc[t - off] : 0;
        __syncthreads();
        sc[t] += add;
        __syncthreads();
    }

    // ---- global reserve + init local cursors ----
    const unsigned cbase = (unsigned)cur[CSENT];
    if (t < NBC) {
        loff[t]  = sc[t] - cnt[t];                 // exclusive
        base_[t] = (int)((unsigned)atomicAdd(&cur[t], cnt[t]) - cbase);
        cnt[t]   = 0;                              // reuse as local cursor
    }
    __syncthreads();

    // ---- scatter into LDS (sorted by bin) ----
    for (int i = t; i < ASLICE; i += 256) {
        const int e = e0 + i;
        const int d = ei[N_EDGES + e];
        const int s = ei[e];
        const int bin = d >> 6;
        const int p = atomicAdd(&cnt[bin], 1);
        sorted[loff[bin] + p] = (s << 6) | (d & 63);
    }
    __syncthreads();

    // ---- flush: 16-lane groups write contiguous per-bin runs ----
    const int g = t >> 4, sl = t & 15;
    for (int bin = g; bin < NBC; bin += 16) {
        const int c  = cnt[bin];
        const int gb = base_[bin];
        const int lo = loff[bin];
        for (int k = sl; k < c; k += 16) {
            const int pos = gb + k;
            if (pos < BCAPC) recs[bin * BCAPC + pos] = sorted[lo + k];
        }
    }
}

// =====================================================================
// K2: fill + gather + MLP + striped BN-stat partials.
// R20: fill + gather R14-EXACT. ONE change: READLANE MLP (R15's fix
// (b), finally isolated — R15 bundled it with a broken gather). Issue
// arithmetic: old MLP = 512 broadcast ds_read_b32/wave; chip-wide
// 2.56M LDS ops / 256 CU = 10K ops on each CU's SINGLE LDS pipe at
// ~5.8cy (m134) = ~24us of serialized LDS issue — the k_gfill cost
// that every gather/TLP restructure failed to touch (R13-R19).
// New: stage rows to regs (8 stride-1 ds_reads/thread, 2-way = free),
// broadcast h[k] via v_readlane (VALU: 4 SIMDs parallel, 15-26% busy).
// Numerically exact (same values, same k order).
// =====================================================================
__global__ __launch_bounds__(256) void k_gfill(
    const float* __restrict__ x,
    const half8_t* __restrict__ xh8,
    const int* __restrict__ cur,
    const int* __restrict__ recs,
    const float* __restrict__ W,
    const float* __restrict__ bias,
    float* __restrict__ out,     // pre-BN h, fp32
    float* __restrict__ stats)   // [NSTRIPE][256] + sentinel
{
    __shared__ u16 lst[RPB * CAP];   // 2 KB: per-node src lists
    __shared__ int cnt[RPB];
    __shared__ float hs[RPB][D];     // 4 KB: gathered rows, then reduce scratch
    const int tid  = threadIdx.x;
    const int bin  = blockIdx.x;
    const int cb   = bin >> 3;           // coarse bin (64 nodes)
    const int sub  = bin & 7;            // this block's 8-node slice
    const int wv   = tid >> 6;
    const int lane = tid & 63;
    const int qq   = lane >> 4;          // quad 0..3: which edge of a 4-edge group
    const int l    = lane & 15;          // owns cols 8l..8l+7
    const float4* __restrict__ x4 = (const float4*)x;

    if (tid < RPB) cnt[tid] = 0;
    __syncthreads();

    // ---- Fill: scan coarse bin's records, keep this sub-bin's (R14) ----
    const unsigned cbase = (unsigned)cur[CSENT];
    int nrec = (int)((unsigned)cur[cb] - cbase);
    if (nrec > BCAPC) nrec = BCAPC;
    const int* __restrict__ br = recs + cb * BCAPC;
    for (int i = tid; i < nrec; i += 256) {
        const int r = br[i];
        if (((r >> 3) & 7) == sub) {
            const int p = atomicAdd(&cnt[r & 7], 1);
            if (p < CAP) lst[(r & 7) * CAP + p] = (u16)(r >> 6);
        }
    }
    __syncthreads();

    // ---- Gather: wave wv handles nodes 2wv, 2wv+1 (R14-exact) ----
    #pragma unroll
    for (int j = 0; j < 2; j++) {
        const int lrow = wv * 2 + j;
        const int node = bin * RPB + lrow;
        int n = cnt[lrow];
        if (n > CAP) n = CAP;
        const u16* __restrict__ myl = &lst[lrow * CAP];
        float acc[8];
        #pragma unroll
        for (int z = 0; z < 8; z++) acc[z] = 0.f;

        int i = 0;
        for (; i + 64 <= n; i += 64) {       // full 64-edge chunk: 16 quads
            const int sj = (int)myl[i + lane];
            #pragma unroll
            for (int b = 0; b < 2; b++) {
                half8_t v[8];
                #pragma unroll
                for (int u = 0; u < 8; u++) {
                    const int s = __shfl(sj, 4 * (b * 8 + u) + qq, 64);
                    v[u] = xh8[(size_t)s * 16 + l];   // 16B, 8 in flight x 4 rows
                }
                #pragma unroll
                for (int u = 0; u < 8; u++)
                    #pragma unroll
                    for (int z = 0; z < 8; z++)
                        acc[z] += (float)v[u][z];
            }
        }
        const int c = n - i;
        if (c > 0) {
            const int sj = (lane < c) ? (int)myl[i + lane] : 0;
            const int quads = c >> 2;
            for (int t2 = 0; t2 < quads; t2 += 8) {
                half8_t v[8];
                #pragma unroll
                for (int u = 0; u < 8; u++) {
                    const int s = __shfl(sj, (4 * (t2 + u) + qq) & 63, 64);
                    v[u] = xh8[(size_t)s * 16 + l];   // safe addr (sj=0 pad)
                }
                #pragma unroll
                for (int u = 0; u < 8; u++) {
                    if (t2 + u < quads) {             // wave-uniform predicate
                        #pragma unroll
                        for (int z = 0; z < 8; z++)
                            acc[z] += (float)v[u][z];
                    }
                }
            }
            const int r = c & 3;
            if (r > 0) {                              // last 1-3 edges
                const int s = __shfl(sj, (4 * quads + qq) & 63, 64);
                const half8_t vv = xh8[(size_t)s * 16 + l];
                if (qq < r) {
                    #pragma unroll
                    for (int z = 0; z < 8; z++)
                        acc[z] += (float)vv[z];
                }
            }
        }
        // combine the 4 quad groups
        #pragma unroll
        for (int z = 0; z < 8; z++) {
            acc[z] += __shfl_xor(acc[z], 16, 64);
            acc[z] += __shfl_xor(acc[z], 32, 64);
        }
        if (qq == 0) {
            const float4 xa = x4[(size_t)node * 32 + 2 * l];      // self term fp32
            const float4 xb = x4[(size_t)node * 32 + 2 * l + 1];  // (eps = 0)
            *(float4*)&hs[lrow][8 * l] =
                make_float4(acc[0] + xa.x, acc[1] + xa.y, acc[2] + xa.z, acc[3] + xa.w);
            *(float4*)&hs[lrow][8 * l + 4] =
                make_float4(acc[4] + xb.x, acc[5] + xb.y, acc[6] + xb.z, acc[7] + xb.w);
        }
    }
    __syncthreads();

    // ---- MLP: thread owns col = tid&127, rows rg*4..rg*4+3 ----
    // R20: stage rows to regs (lane L holds h[row][L], h[row][64+L]),
    // broadcast via v_readlane — k-loop is LDS-free, VALU-parallel.
    const int col = tid & 127;
    const int rg  = tid >> 7;
    float hlo[4], hhi[4];
    #pragma unroll
    for (int r = 0; r < 4; r++) {
        hlo[r] = hs[rg * 4 + r][lane];        // stride-1, 2-way alias = free
        hhi[r] = hs[rg * 4 + r][64 + lane];
    }
    float a[4] = {0.f, 0.f, 0.f, 0.f};
    const float* __restrict__ wc = W + col;
    #pragma unroll 8
    for (int k = 0; k < 64; k++) {
        const float w = wc[k * D];             // 256B/wave coalesced, L1-hot
        #pragma unroll
        for (int r = 0; r < 4; r++)
            a[r] = fmaf(rdlane(hlo[r], k), w, a[r]);
    }
    #pragma unroll 8
    for (int k = 0; k < 64; k++) {
        const float w = wc[(64 + k) * D];
        #pragma unroll
        for (int r = 0; r < 4; r++)
            a[r] = fmaf(rdlane(hhi[r], k), w, a[r]);
    }

    const float bcol = bias[col];
    float s1 = 0.f, s2 = 0.f;
    #pragma unroll
    for (int r = 0; r < 4; r++) {
        const float v = fmaxf(a[r] + bcol, 0.f);
        __builtin_nontemporal_store(v, &out[(size_t)(bin * RPB + rg * 4 + r) * D + col]);
        s1 += v;
        s2 += v * v;
    }

    // ---- BN stat partials: block-reduce, striped atomics ----
    __syncthreads();
    float* red = &hs[0][0];
    red[tid]       = s1;
    red[256 + tid] = s2;
    __syncthreads();
    if (tid < D) {
        float* sp = &stats[(size_t)(bin & (NSTRIPE - 1)) * 256];
        atomicAdd(&sp[tid],     red[tid]       + red[tid + 128]);
        atomicAdd(&sp[D + tid], red[256 + tid] + red[256 + tid + 128]);
    }
}

// =====================================================================
// K3: reduce NSTRIPE stat copies (minus poison base) + BN apply.
// Pure stream over out: nt both directions (native ext-vector type —
// HIP's float4 class is rejected by the nontemporal builtins).
// =====================================================================
__global__ __launch_bounds__(256) void k_bn(
    float* out,
    const float* __restrict__ stats,
    const float* __restrict__ gamma,
    const float* __restrict__ beta)
{
    __shared__ float sc_[D], sh[D];
    const int tid = threadIdx.x;
    if (tid < D) {
        const float fbase = stats[NSTRIPE * 256];   // untouched sentinel
        float s = 0.f, q = 0.f;
        #pragma unroll
        for (int cp = 0; cp < NSTRIPE; cp++) {
            s += stats[cp * 256 + tid]     - fbase;
            q += stats[cp * 256 + D + tid] - fbase;
        }
        const float mean = s * (1.0f / N_NODES);
        const float var  = q * (1.0f / N_NODES) - mean * mean;
        const float scale = gamma[tid] * rsqrtf(var + BN_EPS);
        sc_[tid] = scale;
        sh[tid] = beta[tid] - mean * scale;
    }
    __syncthreads();

    f32x4* o4 = (f32x4*)out;
    #pragma unroll
    for (int j = 0; j < 2; j++) {
        const int f = blockIdx.x * 512 + j * 256 + tid;
        const int c = (f & 31) << 2;
        f32x4 v = __builtin_nontemporal_load(&o4[f]);
        v.x = v.x * sc_[c]     + sh[c];
        v.y = v.y * sc_[c + 1] + sh[c + 1];
        v.z = v.z * sc_[c + 2] + sh[c + 2];
        v.w = v.w * sc_[c + 3] + sh[c + 3];
        __builtin_nontemporal_store(v, &o4[f]);
    }
}

extern "C" void kernel_launch(void* const* d_in, const int* in_sizes, int n_in,
                              void* d_out, int out_size, void* d_ws, size_t ws_size,
                              hipStream_t stream)
{
    const float* x     = (const float*)d_in[0];  // [10000,128] fp32
    const int*   ei    = (const int*)d_in[1];    // [2,640000] int32
    const float* W     = (const float*)d_in[2];  // [128,128] fp32
    const float* bias  = (const float*)d_in[3];  // [128] fp32
    const float* gamma = (const float*)d_in[4];  // [128] fp32
    const float* beta  = (const float*)d_in[5];  // [128] fp32
    float* out = (float*)d_out;                  // [10000,128] fp32

    // ws layout (~5.5 MB), no memset (poison sentinels):
    // [stats 16*256+8 f32][cur 1280 i32][recs NBC*BCAPC i32][xh 10000*128 fp16]
    float*   stats = (float*)d_ws;
    int*     cur   = (int*)(stats + NSTRIPE * 256 + 8);
    int*     recs  = cur + 1280;
    half8_t* xh    = (half8_t*)(recs + NBC * BCAPC);
    // xh byte offset = (4104 + 1280 + 723456)*4 = 2,915,360 -> 16B-aligned

    k_bin<<<ABLK, 256, 0, stream>>>(ei, (const float4*)x, cur, recs, xh);
    k_gfill<<<NB, 256, 0, stream>>>(x, xh, cur, recs, W, bias, out, stats);
    k_bn<<<N_NODES * D / 2048, 256, 0, stream>>>(out, stats, gamma, beta);
}

// Round 11
// 118.633 us; speedup vs baseline: 1.0536x; 1.0271x over previous
//
#include <hip/hip_runtime.h>

#define N_NODES 10000
#define N_EDGES 640000
#define D 128
#define BN_EPS 1e-5f
#define CAP 128        // slots per node; deg ~ Poisson(64), max ~110
#define NSTRIPE 16     // striped BN-stat copies
#define RPB 8          // nodes per block in k_gfill
#define NB 1250        // k_gfill blocks: 8 nodes each (1250*8 = 10000 exact)
#define NBC 157        // coarse bins of 64 nodes (d>>6; 157*64 = 10048)
#define BCAPC 4608     // record capacity per coarse bin (mean 4076, +8.3 sigma)
#define ABLK 256       // pass-A blocks
#define ASLICE 2500    // edges per pass-A block (256*2500 = 640000)
#define CSENT 1250     // untouched cur[] slot = uniform ws fill value (poison base)

typedef _Float16 half8_t __attribute__((ext_vector_type(8)));
typedef float f32x4 __attribute__((ext_vector_type(4)));   // NT-capable float4
typedef unsigned short u16;

// =====================================================================
// K1: bin edges by dst>>6 (COARSE 64-node bins) + x->fp16.  R14-exact.
// Discard pile (R13-R20): k_bin occupancy / store-coalescing / atomic-
// free layouts; gather ILP-with-padding (x3), gather TLP, readlane MLP
// (LDS broadcast reads are free — same-address = broadcast).
// Record = (s<<6)|(d&63): low 3 bits = node-in-8, bits 3..5 = sub-bin.
// =====================================================================
__global__ __launch_bounds__(256) void k_bin(
    const int* __restrict__ ei,
    const float4* __restrict__ x4,
    int* cur,                      // [1280], poison-based cursors (0..156 used)
    int* __restrict__ recs,        // [NBC*BCAPC], packed (s<<6 | d&63)
    half8_t* __restrict__ xh)
{
    __shared__ int cnt[NBC];       // per-bin count, then local cursor
    __shared__ int base_[NBC];     // global reserved start (rel. to poison base)
    __shared__ int loff[NBC];      // exclusive prefix sum (LDS sort offsets)
    __shared__ int sc[256];        // scan scratch
    __shared__ int sorted[ASLICE]; // 10 KB: block's records sorted by bin
    const int b = blockIdx.x, t = threadIdx.x;

    // x -> fp16 (coalesced 16B stores; ~2.5 half8 per thread)
    {
        const int n8 = N_NODES * D / 8;    // 160000
        for (int i = b * 256 + t; i < n8; i += ABLK * 256) {
            const float4 a = x4[2 * i];
            const float4 c = x4[2 * i + 1];
            half8_t h;
            h[0] = (_Float16)a.x; h[1] = (_Float16)a.y;
            h[2] = (_Float16)a.z; h[3] = (_Float16)a.w;
            h[4] = (_Float16)c.x; h[5] = (_Float16)c.y;
            h[6] = (_Float16)c.z; h[7] = (_Float16)c.w;
            xh[i] = h;
        }
    }

    if (t < NBC) cnt[t] = 0;
    __syncthreads();

    // ---- count pass ----
    const int e0 = b * ASLICE;
    for (int i = t; i < ASLICE; i += 256)
        atomicAdd(&cnt[ei[N_EDGES + e0 + i] >> 6], 1);
    __syncthreads();

    // ---- exclusive prefix sum (Hillis-Steele over padded 256) ----
    sc[t] = (t < NBC) ? cnt[t] : 0;
    __syncthreads();
    #pragma unroll
    for (int off = 1; off < 256; off <<= 1) {
        const int add = (t >= off) ? sc[t - off] : 0;
        __syncthreads();
        sc[t] += add;
        __syncthreads();
    }

    // ---- global reserve + init local cursors ----
    const unsigned cbase = (unsigned)cur[CSENT];
    if (t < NBC) {
        loff[t]  = sc[t] - cnt[t];                 // exclusive
        base_[t] = (int)((unsigned)atomicAdd(&cur[t], cnt[t]) - cbase);
        cnt[t]   = 0;                              // reuse as local cursor
    }
    __syncthreads();

    // ---- scatter into LDS (sorted by bin) ----
    for (int i = t; i < ASLICE; i += 256) {
        const int e = e0 + i;
        const int d = ei[N_EDGES + e];
        const int s = ei[e];
        const int bin = d >> 6;
        const int p = atomicAdd(&cnt[bin], 1);
        sorted[loff[bin] + p] = (s << 6) | (d & 63);
    }
    __syncthreads();

    // ---- flush: 16-lane groups write contiguous per-bin runs ----
    const int g = t >> 4, sl = t & 15;
    for (int bin = g; bin < NBC; bin += 16) {
        const int c  = cnt[bin];
        const int gb = base_[bin];
        const int lo = loff[bin];
        for (int k = sl; k < c; k += 16) {
            const int pos = gb + k;
            if (pos < BCAPC) recs[bin * BCAPC + pos] = sorted[lo + k];
        }
    }
}

// =====================================================================
// K2: fill + gather + MLP + striped BN-stat partials.
// R21: WORK-NEUTRAL DEPTH-16 gather. The one experiment R15/R16/R18
// never ran cleanly: R14's gather at exactly the same instruction count
// but with the two 8-deep sub-batches merged into one 16-deep batch
// (full chunk: b=0,1 merged; tail: t2=0,8 merged; identical shfl
// indices, identical FP order -> bit-identical output). In-flight
// model: R14 = ~19.5 waves/CU x 8 = 156 loads -> 164MB gather ~27us;
// 16-deep at >=16 waves/CU -> ~15-18us. __launch_bounds__(256,4) pins
// <=128 VGPR / 16 waves/CU (v[16]=64 VGPR fits; R18's regression fit
// the >128 VGPR wave-halving cliff exactly — avoid it).
// Fill + MLP + BN: R14 byte-for-byte.
// =====================================================================
__global__ __launch_bounds__(256, 4) void k_gfill(
    const float* __restrict__ x,
    const half8_t* __restrict__ xh8,
    const int* __restrict__ cur,
    const int* __restrict__ recs,
    const float* __restrict__ W,
    const float* __restrict__ bias,
    float* __restrict__ out,     // pre-BN h, fp32
    float* __restrict__ stats)   // [NSTRIPE][256] + sentinel
{
    __shared__ u16 lst[RPB * CAP];   // 2 KB: per-node src lists
    __shared__ int cnt[RPB];
    __shared__ float hs[RPB][D];     // 4 KB: gathered rows, then reduce scratch
    const int tid  = threadIdx.x;
    const int bin  = blockIdx.x;
    const int cb   = bin >> 3;           // coarse bin (64 nodes)
    const int sub  = bin & 7;            // this block's 8-node slice
    const int wv   = tid >> 6;
    const int lane = tid & 63;
    const int qq   = lane >> 4;          // quad 0..3: which edge of a 4-edge group
    const int l    = lane & 15;          // owns cols 8l..8l+7
    const float4* __restrict__ x4 = (const float4*)x;

    if (tid < RPB) cnt[tid] = 0;
    __syncthreads();

    // ---- Fill: scan coarse bin's records, keep this sub-bin's (R14) ----
    const unsigned cbase = (unsigned)cur[CSENT];
    int nrec = (int)((unsigned)cur[cb] - cbase);
    if (nrec > BCAPC) nrec = BCAPC;
    const int* __restrict__ br = recs + cb * BCAPC;
    for (int i = tid; i < nrec; i += 256) {
        const int r = br[i];
        if (((r >> 3) & 7) == sub) {
            const int p = atomicAdd(&cnt[r & 7], 1);
            if (p < CAP) lst[(r & 7) * CAP + p] = (u16)(r >> 6);
        }
    }
    __syncthreads();

    // ---- Gather: wave wv handles nodes 2wv, 2wv+1; 16-deep batches ----
    #pragma unroll
    for (int j = 0; j < 2; j++) {
        const int lrow = wv * 2 + j;
        const int node = bin * RPB + lrow;
        int n = cnt[lrow];
        if (n > CAP) n = CAP;
        const u16* __restrict__ myl = &lst[lrow * CAP];
        float acc[8];
        #pragma unroll
        for (int z = 0; z < 8; z++) acc[z] = 0.f;

        int i = 0;
        for (; i + 64 <= n; i += 64) {       // full 64-edge chunk: 16 quads
            const int sj = (int)myl[i + lane];
            half8_t v[16];
            #pragma unroll
            for (int u = 0; u < 16; u++) {   // ALL 16 loads issued back-to-back
                const int s = __shfl(sj, 4 * u + qq, 64);
                v[u] = xh8[(size_t)s * 16 + l];   // 16B, 16 in flight
            }
            #pragma unroll
            for (int u = 0; u < 16; u++)
                #pragma unroll
                for (int z = 0; z < 8; z++)
                    acc[z] += (float)v[u][z];     // same u-order as R14
        }
        const int c = n - i;
        if (c > 0) {
            const int sj = (lane < c) ? (int)myl[i + lane] : 0;
            const int quads = c >> 2;             // 0..15
            const int r = c & 3;
            half8_t v[16];
            #pragma unroll
            for (int u = 0; u < 16; u++) {        // unconditional, wrapped idx
                const int s = __shfl(sj, (4 * u + qq) & 63, 64);
                v[u] = xh8[(size_t)s * 16 + l];   // safe addr (sj=0 pad)
            }
            #pragma unroll
            for (int u = 0; u < 16; u++) {
                if (u < quads) {                  // wave-uniform predicate
                    #pragma unroll
                    for (int z = 0; z < 8; z++)
                        acc[z] += (float)v[u][z];
                } else if (u == quads && qq < r) { // remainder quad (per-lane)
                    #pragma unroll
                    for (int z = 0; z < 8; z++)
                        acc[z] += (float)v[u][z];
                }
            }
        }
        // combine the 4 quad groups
        #pragma unroll
        for (int z = 0; z < 8; z++) {
            acc[z] += __shfl_xor(acc[z], 16, 64);
            acc[z] += __shfl_xor(acc[z], 32, 64);
        }
        if (qq == 0) {
            const float4 xa = x4[(size_t)node * 32 + 2 * l];      // self term fp32
            const float4 xb = x4[(size_t)node * 32 + 2 * l + 1];  // (eps = 0)
            *(float4*)&hs[lrow][8 * l] =
                make_float4(acc[0] + xa.x, acc[1] + xa.y, acc[2] + xa.z, acc[3] + xa.w);
            *(float4*)&hs[lrow][8 * l + 4] =
                make_float4(acc[4] + xb.x, acc[5] + xb.y, acc[6] + xb.z, acc[7] + xb.w);
        }
    }
    __syncthreads();

    // ---- MLP: thread owns col = tid&127, rows rg*4..rg*4+3 (R14-exact) ----
    const int col = tid & 127;
    const int rg  = tid >> 7;
    float a[4] = {0.f, 0.f, 0.f, 0.f};
    #pragma unroll 8
    for (int k = 0; k < D; k++) {
        const float w = W[k * D + col];        // 256B/wave coalesced, L1/L2-hot
        #pragma unroll
        for (int r = 0; r < 4; r++)
            a[r] = fmaf(hs[rg * 4 + r][k], w, a[r]);   // LDS broadcast (free)
    }

    const float bcol = bias[col];
    float s1 = 0.f, s2 = 0.f;
    #pragma unroll
    for (int r = 0; r < 4; r++) {
        const float v = fmaxf(a[r] + bcol, 0.f);
        __builtin_nontemporal_store(v, &out[(size_t)(bin * RPB + rg * 4 + r) * D + col]);
        s1 += v;
        s2 += v * v;
    }

    // ---- BN stat partials: block-reduce, striped atomics ----
    __syncthreads();
    float* red = &hs[0][0];
    red[tid]       = s1;
    red[256 + tid] = s2;
    __syncthreads();
    if (tid < D) {
        float* sp = &stats[(size_t)(bin & (NSTRIPE - 1)) * 256];
        atomicAdd(&sp[tid],     red[tid]       + red[tid + 128]);
        atomicAdd(&sp[D + tid], red[256 + tid] + red[256 + tid + 128]);
    }
}

// =====================================================================
// K3: reduce NSTRIPE stat copies (minus poison base) + BN apply.
// Pure stream over out: nt both directions (native ext-vector type —
// HIP's float4 class is rejected by the nontemporal builtins).
// =====================================================================
__global__ __launch_bounds__(256) void k_bn(
    float* out,
    const float* __restrict__ stats,
    const float* __restrict__ gamma,
    const float* __restrict__ beta)
{
    __shared__ float sc_[D], sh[D];
    const int tid = threadIdx.x;
    if (tid < D) {
        const float fbase = stats[NSTRIPE * 256];   // untouched sentinel
        float s = 0.f, q = 0.f;
        #pragma unroll
        for (int cp = 0; cp < NSTRIPE; cp++) {
            s += stats[cp * 256 + tid]     - fbase;
            q += stats[cp * 256 + D + tid] - fbase;
        }
        const float mean = s * (1.0f / N_NODES);
        const float var  = q * (1.0f / N_NODES) - mean * mean;
        const float scale = gamma[tid] * rsqrtf(var + BN_EPS);
        sc_[tid] = scale;
        sh[tid] = beta[tid] - mean * scale;
    }
    __syncthreads();

    f32x4* o4 = (f32x4*)out;
    #pragma unroll
    for (int j = 0; j < 2; j++) {
        const int f = blockIdx.x * 512 + j * 256 + tid;
        const int c = (f & 31) << 2;
        f32x4 v = __builtin_nontemporal_load(&o4[f]);
        v.x = v.x * sc_[c]     + sh[c];
        v.y = v.y * sc_[c + 1] + sh[c + 1];
        v.z = v.z * sc_[c + 2] + sh[c + 2];
        v.w = v.w * sc_[c + 3] + sh[c + 3];
        __builtin_nontemporal_store(v, &o4[f]);
    }
}

extern "C" void kernel_launch(void* const* d_in, const int* in_sizes, int n_in,
                              void* d_out, int out_size, void* d_ws, size_t ws_size,
                              hipStream_t stream)
{
    const float* x     = (const float*)d_in[0];  // [10000,128] fp32
    const int*   ei    = (const int*)d_in[1];    // [2,640000] int32
    const float* W     = (const float*)d_in[2];  // [128,128] fp32
    const float* bias  = (const float*)d_in[3];  // [128] fp32
    const float* gamma = (const float*)d_in[4];  // [128] fp32
    const float* beta  = (const float*)d_in[5];  // [128] fp32
    float* out = (float*)d_out;                  // [10000,128] fp32

    // ws layout (~5.5 MB), no memset (poison sentinels):
    // [stats 16*256+8 f32][cur 1280 i32][recs NBC*BCAPC i32][xh 10000*128 fp16]
    float*   stats = (float*)d_ws;
    int*     cur   = (int*)(stats + NSTRIPE * 256 + 8);
    int*     recs  = cur + 1280;
    half8_t* xh    = (half8_t*)(recs + NBC * BCAPC);
    // xh byte offset = (4104 + 1280 + 723456)*4 = 2,915,360 -> 16B-aligned

    k_bin<<<ABLK, 256, 0, stream>>>(ei, (const float4*)x, cur, recs, xh);
    k_gfill<<<NB, 256, 0, stream>>>(x, xh, cur, recs, W, bias, out, stats);
    k_bn<<<N_NODES * D / 2048, 256, 0, stream>>>(out, stats, gamma, beta);
}